// Round 11
// baseline (115.095 us; speedup 1.0000x reference)
//
#include <hip/hip_runtime.h>
#include <cstdint>

#define NTOK 65536
#define DIM 240
#define KP 256
#define NMETA 576
#define NGB 512          // gating/permute blocks (128 tokens each)

typedef short bf16x8 __attribute__((ext_vector_type(8)));
typedef float f32x16 __attribute__((ext_vector_type(16)));

union U16B { uint4 u; bf16x8 v; };

__device__ __forceinline__ unsigned short f2bf(float x) {
  unsigned int u = __float_as_uint(x);
  u += 0x7fffu + ((u >> 16) & 1u);     // RNE
  return (unsigned short)(u >> 16);
}

// DPP move helpers (VALU pipe). 0xB1 = quad_perm xor1, 0x4E = quad_perm xor2,
// 0x128 = row_ror:8 (== xor8 within a 16-lane row).
template<int CTRL>
__device__ __forceinline__ float dppf(float v) {
  return __int_as_float(__builtin_amdgcn_update_dpp(0, __float_as_int(v), CTRL, 0xF, 0xF, true));
}
template<int CTRL>
__device__ __forceinline__ unsigned dppu(unsigned v) {
  return (unsigned)__builtin_amdgcn_update_dpp(0, (int)v, CTRL, 0xF, 0xF, true);
}
__device__ __forceinline__ bool pgt(unsigned a, unsigned b) {
  float fa = __uint_as_float(a & ~7u), fb = __uint_as_float(b & ~7u);
  return (fa != fb) ? (fa > fb) : ((a & 7u) < (b & 7u));
}
template<int CTRL>
__device__ __forceinline__ void top2round(unsigned& a1, unsigned& a2) {
  unsigned b1 = dppu<CTRL>(a1), b2 = dppu<CTRL>(a2);
  bool g = pgt(a1, b1);
  unsigned n1 = g ? a1 : b1;
  unsigned lo = g ? b1 : a1;
  unsigned m2 = pgt(a2, b2) ? a2 : b2;
  a2 = pgt(lo, m2) ? lo : m2;
  a1 = n1;
}

// ---------------- kernel 1: pack expert weights, granule-major: WbT[e][g32][col256][16B]
__global__ __launch_bounds__(256) void prep_w(const float* __restrict__ ew,
                                              unsigned short* __restrict__ WbT) {
  int idx = blockIdx.x * 256 + threadIdx.x;     // e(8) x n(256) x k-quad(64)
  int k0 = (idx & 63) << 2;
  int n  = (idx >> 6) & 255;
  int e  = idx >> 14;
  ushort4 v = {0, 0, 0, 0};
  if (n < DIM && k0 < DIM) {
    const float* wrow = ew + (e * DIM + n) * DIM;
    v.x = f2bf(wrow[k0]); v.y = f2bf(wrow[k0 + 1]);
    v.z = f2bf(wrow[k0 + 2]); v.w = f2bf(wrow[k0 + 3]);
  }
  // dest: granule (k0>>3), within-granule ushort (k0&7)
  *(ushort4*)&WbT[((size_t)(e * 32 + (k0 >> 3)) * 256 + n) * 8 + (k0 & 7)] = v;
}

// ---------------- kernel 2: gating (DPP reduce), writes pairid/wpair/hist only
__global__ __launch_bounds__(512) void gating(const float* __restrict__ x,
                                              const float* __restrict__ gw,
                                              const float* __restrict__ gb,
                                              unsigned char* __restrict__ pairid,
                                              float2* __restrict__ wpair,
                                              int* __restrict__ hist2d) {
  __shared__ __align__(16) float gwT[8][DIM];
  __shared__ int hist[64];
  for (int i = threadIdx.x; i < 8 * DIM; i += 512) gwT[i & 7][i >> 3] = gw[i];
  if (threadIdx.x < 64) hist[threadIdx.x] = 0;
  __syncthreads();
  const int lane = threadIdx.x & 63;
  const int w = threadIdx.x >> 6;
  const bool act = lane < 60;
  float4 g[8];
#pragma unroll
  for (int e = 0; e < 8; ++e)
    g[e] = act ? *(const float4*)(&gwT[e][lane * 4]) : make_float4(0.f, 0.f, 0.f, 0.f);
  const int elane = 4 * (lane & 1) + 2 * ((lane >> 1) & 1) + ((lane >> 3) & 1);
  const float gbl = gb[elane];
  const int tbase = blockIdx.x * 128 + w * 16;
  for (int it = 0; it < 16; ++it) {
    const int t = tbase + it;
    float4 xv = act ? *(const float4*)(x + (size_t)t * DIM + lane * 4)
                    : make_float4(0.f, 0.f, 0.f, 0.f);
    float p[8];
#pragma unroll
    for (int e = 0; e < 8; ++e)
      p[e] = xv.x * g[e].x + xv.y * g[e].y + xv.z * g[e].z + xv.w * g[e].w;
    float q4[4];
#pragma unroll
    for (int i = 0; i < 4; ++i) {
      float lo = p[i] + dppf<0xB1>(p[i]);
      float hi = p[i + 4] + dppf<0xB1>(p[i + 4]);
      q4[i] = (lane & 1) ? hi : lo;
    }
    float q2[2];
#pragma unroll
    for (int i = 0; i < 2; ++i) {
      float lo = q4[i] + dppf<0x4E>(q4[i]);
      float hi = q4[i + 2] + dppf<0x4E>(q4[i + 2]);
      q2[i] = (lane & 2) ? hi : lo;
    }
    float lo = q2[0] + dppf<0x128>(q2[0]);
    float hi = q2[1] + dppf<0x128>(q2[1]);
    float s = (lane & 8) ? hi : lo;
    s += __shfl_xor(s, 4);
    s += __shfl_xor(s, 16);
    s += __shfl_xor(s, 32);
    s += gbl;
    unsigned a1 = (__float_as_uint(s) & ~7u) | (unsigned)elane;
    unsigned a2 = (0xFF800000u & ~7u) | 7u;
    top2round<0xB1>(a1, a2);
    top2round<0x4E>(a1, a2);
    top2round<0x128>(a1, a2);
    if (lane == 0) {
      const int i1 = a1 & 7, i2 = a2 & 7;
      const float l1 = __uint_as_float(a1 & ~7u), l2 = __uint_as_float(a2 & ~7u);
      const float qq = expf(l2 - l1);
      const float w1 = 1.f / (1.f + qq);
      const float w2 = qq / (1.f + qq);
      const int ea = (i1 < i2) ? i1 : i2, eb2 = (i1 < i2) ? i2 : i1;
      const float wa = (i1 < i2) ? w1 : w2, wb2 = (i1 < i2) ? w2 : w1;
      const int pp = ea * 8 + eb2;
      pairid[t] = (unsigned char)pp;
      wpair[t] = make_float2(wa, wb2);
      atomicAdd(&hist[pp], 1);                  // LDS only
    }
  }
  __syncthreads();
  if (threadIdx.x < 64) hist2d[blockIdx.x * 64 + threadIdx.x] = hist[threadIdx.x];
}

// ---------------- kernel 3: per-pair exclusive scan over 512 block-hists (64 blocks)
__global__ __launch_bounds__(512) void scan1_k(const int* __restrict__ hist2d,
                                               int* __restrict__ lbase2d,
                                               int* __restrict__ cnt) {
  __shared__ int s[NGB];
  const int p = blockIdx.x, tid = threadIdx.x;
  const int v = hist2d[tid * 64 + p];
  s[tid] = v;
  __syncthreads();
  for (int off = 1; off < NGB; off <<= 1) {
    int tv = (tid >= off) ? s[tid - off] : 0;
    __syncthreads();
    s[tid] += tv;
    __syncthreads();
  }
  lbase2d[tid * 64 + p] = s[tid] - v;
  if (tid == NGB - 1) cnt[p] = s[tid];
}

// ---------------- kernel 4: pair starts + tile meta (128-token tiles)
__global__ void scan2_k(const int* __restrict__ cnt, int* __restrict__ start,
                        int4* __restrict__ meta) {
  __shared__ int sc[64], sstart[64], stile[64], stot;
  const int tid = threadIdx.x;
  sc[tid] = cnt[tid];
  __syncthreads();
  if (tid == 0) {
    int a = 0, ta = 0;
    for (int p = 0; p < 64; ++p) { sstart[p] = a; stile[p] = ta; a += sc[p]; ta += (sc[p] + 127) >> 7; }
    stot = ta;
  }
  __syncthreads();
  start[tid] = sstart[tid];
  const int c = sc[tid], e0 = tid >> 3, e1 = tid & 7;
  for (int i = 0; (i << 7) < c; ++i)
    meta[stile[tid] + i] = make_int4(e0, e1, sstart[tid] + (i << 7), min(128, c - (i << 7)));
  for (int j = stot + tid; j < NMETA; j += 64)
    meta[j] = make_int4(0, 0, 0, 0);
}

// ---------------- kernel 5: permute + f32->bf16 pack: xbs[pos][256], wsorted, tokord
__global__ __launch_bounds__(512) void permute_k(const float* __restrict__ x,
                                                 const unsigned char* __restrict__ pairid,
                                                 const float2* __restrict__ wpair,
                                                 const int* __restrict__ start,
                                                 const int* __restrict__ lbase2d,
                                                 unsigned short* __restrict__ xbs,
                                                 float2* __restrict__ wsorted,
                                                 int* __restrict__ tokord) {
  __shared__ int lcnt[64], sp[128];
  const int b = blockIdx.x, tid = threadIdx.x;
  if (tid < 64) lcnt[tid] = 0;
  __syncthreads();
  if (tid < 128) {
    const int t = b * 128 + tid;
    const int p = pairid[t];
    const int rank = atomicAdd(&lcnt[p], 1);     // LDS only
    const int pos = start[p] + lbase2d[b * 64 + p] + rank;
    sp[tid] = pos;
    wsorted[pos] = wpair[t];
    tokord[pos] = t;
  }
  __syncthreads();
  for (int j = tid; j < 128 * 32; j += 512) {
    const int tl = j >> 5, og = j & 31;
    const size_t src = (size_t)(b * 128 + tl) * DIM + og * 8;
    ushort4 o0 = {0, 0, 0, 0}, o1 = {0, 0, 0, 0};
    if (og < 30) {
      const float4 q0 = *(const float4*)(x + src);
      const float4 q1 = *(const float4*)(x + src + 4);
      o0.x = f2bf(q0.x); o0.y = f2bf(q0.y); o0.z = f2bf(q0.z); o0.w = f2bf(q0.w);
      o1.x = f2bf(q1.x); o1.y = f2bf(q1.y); o1.z = f2bf(q1.z); o1.w = f2bf(q1.w);
    }
    unsigned short* dst = xbs + (size_t)sp[tl] * KP + og * 8;
    *(ushort4*)dst = o0;
    *(ushort4*)(dst + 4) = o1;
  }
}

// ---------------- kernel 6: pair-sparse GEMM, A-resident (coalesced, swizzled),
// W granule-major streamed (coalesced), counted-vmcnt dbuf. 128 tok x 128 col x 2e.
// LDS: A 64K [row128][g-swz 32][16B] + W 16K dbuf [g2][e2][col128][16B] = 80KB -> 2/CU.
#define GLDS16(g, l)                                                        \
  __builtin_amdgcn_global_load_lds(                                         \
      (__attribute__((address_space(1))) unsigned int*)(g),                 \
      (__attribute__((address_space(3))) unsigned int*)(l), 16, 0, 0)

__global__ __launch_bounds__(512, 2) void moe_gemm_pair(const unsigned short* __restrict__ xbs,
                                                        const unsigned short* __restrict__ WbT,
                                                        const float* __restrict__ ebias,
                                                        const float2* __restrict__ wsorted,
                                                        const int* __restrict__ tokord,
                                                        const int4* __restrict__ meta,
                                                        float* __restrict__ out) {
  extern __shared__ __align__(16) char smem[];
  const int4 m = meta[blockIdx.x >> 1];
  const int n = m.w;
  if (n == 0) return;
  const int ch = blockIdx.x & 1;                 // column half
  const int tid = threadIdx.x, lane = tid & 63, wid = tid >> 6;
  const int wr = wid >> 2, wcl = wid & 3;        // 2 row-waves x 4 col-waves (64 tok x 32 col)
  const int l31 = lane & 31, hi = lane >> 5;

  // A prologue: coalesced; source pre-swizzled so LDS granule gl holds global
  // granule gl ^ (row & 31). Each wave-op reads 2 full 512B rows (permuted within).
#pragma unroll
  for (int j = 0; j < 8; ++j) {
    const int o = tid * 16 + j * 8192;
    const int row = o >> 9, gl = (o >> 4) & 31;
    GLDS16((const char*)xbs + (size_t)(m.z + row) * 512 + ((gl ^ (row & 31)) << 4),
           smem + o);
  }
  // W chunk 0 (granules 0,1 for both experts, coalesced 1024B/wave-op)
  const int sg = tid >> 8, se = (tid >> 7) & 1, scol = tid & 127;
  const char* wsrc0 = (const char*)WbT + (size_t)(se ? m.y : m.x) * 131072
                    + (size_t)sg * 4096 + (size_t)(ch * 128 + scol) * 16;
  char* wlds = smem + 65536;
  GLDS16(wsrc0, wlds + tid * 16);
  __syncthreads();                               // full drain, once

  f32x16 acc[2][2] = {};                         // [expert][row-frag]
  const int rA0 = wr * 64 + l31, rA1 = rA0 + 32;
  const char* wrd = wlds + (hi << 12) + ((wcl * 32 + l31) << 4);

  for (int it = 0; it < 15; ++it) {              // K = 15 x 16
    const int buf = it & 1;
    if (it > 0) {                                // readers of buf^1 (prev iter) done
      __builtin_amdgcn_s_barrier();
      __builtin_amdgcn_sched_barrier(0);
    }
    if (it < 14) {
      GLDS16(wsrc0 + (size_t)(it + 1) * 8192, wlds + ((buf ^ 1) << 13) + tid * 16);
      __builtin_amdgcn_sched_barrier(0);
      asm volatile("s_waitcnt vmcnt(1)" ::: "memory");   // chunk `it` landed; it+1 in flight
    } else {
      asm volatile("s_waitcnt vmcnt(0)" ::: "memory");
    }
    __builtin_amdgcn_sched_barrier(0);
    __builtin_amdgcn_s_barrier();                // all waves see buf ready
    __builtin_amdgcn_sched_barrier(0);

    const int G = 2 * it + hi;
    U16B a0, a1, b0, b1;
    a0.u = *(const uint4*)(smem + rA0 * 512 + ((G ^ l31) << 4));
    a1.u = *(const uint4*)(smem + rA1 * 512 + ((G ^ l31) << 4));
    const char* wp = wrd + (buf << 13);
    b0.u = *(const uint4*)(wp);                  // expert m.x
    b1.u = *(const uint4*)(wp + 2048);           // expert m.y
    acc[0][0] = __builtin_amdgcn_mfma_f32_32x32x16_bf16(a0.v, b0.v, acc[0][0], 0, 0, 0);
    acc[0][1] = __builtin_amdgcn_mfma_f32_32x32x16_bf16(a1.v, b0.v, acc[0][1], 0, 0, 0);
    acc[1][0] = __builtin_amdgcn_mfma_f32_32x32x16_bf16(a0.v, b1.v, acc[1][0], 0, 0, 0);
    acc[1][1] = __builtin_amdgcn_mfma_f32_32x32x16_bf16(a1.v, b1.v, acc[1][1], 0, 0, 0);
  }

  // epilogue: out[tok, col] = wa*(P_A + b_A[col]) + wb*(P_B + b_B[col])
  // tokord/wsorted reads are wave-uniform (rw independent of l31) -> scalar loads.
  const int col = ch * 128 + wcl * 32 + l31;
  if (col < DIM) {
    const float be0 = ebias[m.x * DIM + col];
    const float be1 = ebias[m.y * DIM + col];
#pragma unroll
    for (int af = 0; af < 2; ++af) {
#pragma unroll
      for (int r = 0; r < 16; ++r) {
        const int rw = wr * 64 + af * 32 + (r & 3) + ((r >> 2) << 3) + (hi << 2);
        if (rw < n) {
          const int t = tokord[m.z + rw];
          const float2 w2 = wsorted[m.z + rw];
          out[(size_t)t * DIM + col] =
              w2.x * (acc[0][af][r] + be0) + w2.y * (acc[1][af][r] + be1);
        }
      }
    }
  }
}

extern "C" void kernel_launch(void* const* d_in, const int* in_sizes, int n_in,
                              void* d_out, int out_size, void* d_ws, size_t ws_size,
                              hipStream_t stream) {
  const float* x  = (const float*)d_in[0];
  const float* gw = (const float*)d_in[1];
  const float* gb = (const float*)d_in[2];
  const float* ew = (const float*)d_in[3];
  const float* eb = (const float*)d_in[4];
  float* out = (float*)d_out;

  // workspace layout (~36.4 MB)
  char* ws = (char*)d_ws;
  unsigned short* WbT  = (unsigned short*)ws;                          // 1 MB
  unsigned short* xbs  = (unsigned short*)(ws + 1048576);              // (65536+256)*512B
  float2*         wpr  = (float2*)(ws + 34734080);                     // 512 KB
  float2*         wsr  = (float2*)(ws + 35258368);                     // (65536+256)*8B
  int*            tord = (int*)(ws + 35784704);                        // (65536+256)*4B
  unsigned char*  pid  = (unsigned char*)(ws + 36047872);              // 64 KB
  int*            h2d  = (int*)(ws + 36113408);                        // 128 KB
  int*            lb2d = (int*)(ws + 36244480);                        // 128 KB
  int*            cnt  = (int*)(ws + 36375552);                        // 256 B
  int*            strt = (int*)(ws + 36375808);                        // 256 B
  int4*           meta = (int4*)(ws + 36376064);                       // 9.2 KB

  hipFuncSetAttribute((const void*)moe_gemm_pair, hipFuncAttributeMaxDynamicSharedMemorySize, 81920);

  prep_w<<<512, 256, 0, stream>>>(ew, WbT);
  gating<<<NGB, 512, 0, stream>>>(x, gw, gb, pid, wpr, h2d);
  scan1_k<<<64, NGB, 0, stream>>>(h2d, lb2d, cnt);
  scan2_k<<<1, 64, 0, stream>>>(cnt, strt, meta);
  permute_k<<<NGB, 512, 0, stream>>>(x, pid, wpr, strt, lb2d, xbs, wsr, tord);
  moe_gemm_pair<<<2 * NMETA, 512, 81920, stream>>>(xbs, WbT, eb, wsr, tord, meta, out);
}